// Round 2
// baseline (58.429 us; speedup 1.0000x reference)
//
#include <hip/hip_runtime.h>

// Block-mask metadata for flex-attention style sparsity.
// M = N = 32768 tokens, QB = KB = 128 -> 256 x 256 block mask.
//
// bm[qb][kb] = any(q <= kv && doc[q]==doc[kv]) over the 128x128 tile
//            = 0                       if kb < qb
//            = 1                       if kb == qb   (q==kv pair on diagonal)
//            = docs(qb) intersects docs(kb)  if kb > qb (causal always true)
//
// Outputs (flat int32, reference return order):
//   [0,256)                 kv_num_blocks   row sums
//   [256,256+65536)         kv_indices      per-row stable-desc argsort of {0,1}
//   [+256)                  q_num_blocks    column sums
//   [+65536)                q_indices       per-col stable-desc argsort
//   last two                kv_block_size=128, q_block_size=128

#define NBLK 256   // blocks per side
#define TOK  128   // tokens per block

// ---- Kernel 1: per-block doc summary: min, max, uniform?, first ----
__global__ void block_summary_kernel(const int* __restrict__ doc,
                                     int4* __restrict__ sum) {
    const int b = blockIdx.x;      // 256 blocks
    const int t = threadIdx.x;     // 64 threads (1 wave)
    int d0 = doc[b * TOK + t];
    int d1 = doc[b * TOK + 64 + t];
    int mn = min(d0, d1), mx = max(d0, d1);
#pragma unroll
    for (int o = 32; o; o >>= 1) {
        mn = min(mn, __shfl_xor(mn, o));
        mx = max(mx, __shfl_xor(mx, o));
    }
    if (t == 0) sum[b] = make_int4(mn, mx, (mn == mx) ? 1 : 0, d0);
}

// bm value for tile (qb, kb); O(1) fast paths; generic fallback never taken
// for the fixed setup_inputs (every 128-block is doc-uniform).
__device__ __forceinline__ int bm_val(int qb, int kb, const int4* S,
                                      const int* __restrict__ doc) {
    if (kb < qb) return 0;
    if (kb == qb) return 1;
    int4 a = S[qb], b = S[kb];
    if (a.y < b.x || b.y < a.x) return 0;          // doc ranges disjoint
    if (a.z && b.z) return (a.w == b.w) ? 1 : 0;   // both uniform
    for (int i = 0; i < TOK; ++i) {                // generic fallback
        int dq = doc[qb * TOK + i];
        for (int j = 0; j < TOK; ++j)
            if (dq == doc[kb * TOK + j]) return 1;
    }
    return 0;
}

// ---- Kernel 2: workgroup r does row r (kv side) + column r (q side) ----
__global__ __launch_bounds__(256) void mask_out_kernel(
        const int* __restrict__ doc, const int4* __restrict__ sum,
        int* __restrict__ out) {
    const int r = blockIdx.x;      // 0..255
    const int t = threadIdx.x;     // 0..255

    __shared__ int4 S[NBLK];
    __shared__ int wsum[4];
    S[t] = sum[t];
    __syncthreads();

    int* kvn = out;                       // 256
    int* kvi = out + 256;                 // 65536
    int* qn  = out + 256 + 65536;         // 256
    int* qi  = out + 512 + 65536;         // 65536
    // bs scalars at 512 + 2*65536 = 131584, 131585

    const int lane = t & 63;
    const int wv   = t >> 6;

    // ---------- row r: kv_num_blocks / kv_indices ----------
    {
        int v = bm_val(r, t, S, doc);
        unsigned long long m = __ballot(v != 0);
        int prew = __popcll(m & ((1ULL << lane) - 1ULL));
        int wtot = __popcll(m);
        if (lane == 0) wsum[wv] = wtot;
        __syncthreads();
        int base = 0;
        for (int i = 0; i < wv; ++i) base += wsum[i];
        int total = wsum[0] + wsum[1] + wsum[2] + wsum[3];
        int pre = base + prew;                       // ones strictly before t
        int rank = v ? pre : (total + (t - pre));    // stable desc argsort rank
        kvi[r * NBLK + rank] = t;
        if (t == 0) kvn[r] = total;
        __syncthreads();   // wsum reused below
    }

    // ---------- column r: q_num_blocks / q_indices ----------
    {
        int v = bm_val(t, r, S, doc);
        unsigned long long m = __ballot(v != 0);
        int prew = __popcll(m & ((1ULL << lane) - 1ULL));
        int wtot = __popcll(m);
        if (lane == 0) wsum[wv] = wtot;
        __syncthreads();
        int base = 0;
        for (int i = 0; i < wv; ++i) base += wsum[i];
        int total = wsum[0] + wsum[1] + wsum[2] + wsum[3];
        int pre = base + prew;
        int rank = v ? pre : (total + (t - pre));
        qi[r * NBLK + rank] = t;
        if (t == 0) qn[r] = total;
    }

    if (r == 0 && t == 0) {
        out[512 + 2 * 65536 + 0] = 128;   // kv_block_size
        out[512 + 2 * 65536 + 1] = 128;   // q_block_size
    }
}

extern "C" void kernel_launch(void* const* d_in, const int* in_sizes, int n_in,
                              void* d_out, int out_size, void* d_ws, size_t ws_size,
                              hipStream_t stream) {
    // d_in[0] = x (8x128 f32, unused), d_in[1] = document_id (int32[32768])
    const int* doc = (const int*)d_in[1];
    int* out = (int*)d_out;
    int4* sum = (int4*)d_ws;    // 256 * 16 B = 4 KB scratch

    hipLaunchKernelGGL(block_summary_kernel, dim3(NBLK), dim3(64), 0, stream,
                       doc, sum);
    hipLaunchKernelGGL(mask_out_kernel, dim3(NBLK), dim3(256), 0, stream,
                       doc, sum, out);
}